// Round 6
// baseline (468.451 us; speedup 1.0000x reference)
//
#include <hip/hip_runtime.h>

#define KSTATES 64

typedef float v2f __attribute__((ext_vector_type(2)));

__device__ __forceinline__ float wave_max64(float v) {
#pragma unroll
  for (int off = 32; off; off >>= 1) v = fmaxf(v, __shfl_xor(v, off, 64));
  return v;
}

__device__ __forceinline__ float wave_sum64(float v) {
#pragma unroll
  for (int off = 32; off; off >>= 1) v += __shfl_xor(v, off, 64);
  return v;
}

__device__ __forceinline__ float bcast0(float v) {
  return __int_as_float(__builtin_amdgcn_readfirstlane(__float_as_int(v)));
}

// Broadcast matvec: s = sum_i buf[i] * c[i], buf read as wave-uniform float4
// broadcasts (same-address LDS reads: conflict-free, in-order returns ->
// progressive lgkmcnt), MACs as packed-f32 pairs (v_pk_fma_f32: 2 MACs/inst).
// 4 v2f accumulator chains; combine order fixed.
__device__ __forceinline__ float matvec64(const float* buf, const v2f* c2) {
  const float4* Av = (const float4*)buf;
  v2f a0 = {0.f, 0.f}, a1 = {0.f, 0.f}, a2 = {0.f, 0.f}, a3 = {0.f, 0.f};
#pragma unroll
  for (int p = 0; p < 16; p += 2) {
    float4 u = Av[p];
    v2f u0 = {u.x, u.y}, u1 = {u.z, u.w};
    a0 = __builtin_elementwise_fma(u0, c2[2 * p + 0], a0);
    a1 = __builtin_elementwise_fma(u1, c2[2 * p + 1], a1);
    float4 w = Av[p + 1];
    v2f w0 = {w.x, w.y}, w1 = {w.z, w.w};
    a2 = __builtin_elementwise_fma(w0, c2[2 * p + 2], a2);
    a3 = __builtin_elementwise_fma(w1, c2[2 * p + 3], a3);
  }
  v2f s2 = (a0 + a2) + (a1 + a3);
  return s2.x + s2.y;
}

// ONE wave per sequence, running BOTH the forward chain (t = 1..m) and the
// backward chain (t = sl-1..m+1) interleaved. The two chains are
// sequentially independent, so each chain's LDS write->broadcast-read
// turnaround latency (~500 cy exposed in R0/R1, the dominant per-step cost)
// is filled by the other chain's issue. readlane broadcast is abandoned:
// R5 proved v_readlane is execution-rate-limited (~8cy/op on the VALU pipe),
// unfixable by scheduling. Z = sum_j alpha_m[j]*beta_m[j], combined
// in-register (same wave holds both states).
__global__ __launch_bounds__(64)
__attribute__((amdgpu_waves_per_eu(1, 1))) void crf_kernel(
    const float* __restrict__ emissions,   // [B, T, K]
    const float* __restrict__ transitions, // [K, K]
    const float* __restrict__ start_trans, // [K]
    const float* __restrict__ end_trans,   // [K]
    const int* __restrict__ labels,        // [B, T]
    const int* __restrict__ sent_len,      // [B]
    float* __restrict__ out,               // scalar
    int T, float inv_B) {
  const int b = blockIdx.x;
  const int j = threadIdx.x;  // state index == lane
  const int sl = sent_len[b];
  const int tmax = T - 1;

  // Double-buffered per chain: step t+1 writes the opposite buffer from the
  // one step t reads -> no WAR dependency, no second barrier needed (R0).
  __shared__ __align__(16) float bufF[2][KSTATES];
  __shared__ __align__(16) float bufB[2][KSTATES];

  const float* em = emissions + (size_t)b * T * KSTATES;
  const int* lbl = labels + (size_t)b * T;
  const float* emj = em + j;

  // ---- gold score: lane-parallel over time (independent, pipelined) ----
  float g = 0.f;
#pragma unroll 4
  for (int t0 = j; t0 < T; t0 += KSTATES) {
    if (t0 < sl) {
      int lab = lbl[t0];
      float v = em[(size_t)t0 * KSTATES + lab];
      if (t0 == 0)
        v += start_trans[lab];
      else
        v += transitions[lbl[t0 - 1] * KSTATES + lab];
      if (t0 == sl - 1) v += end_trans[lab];
      g += v;
    }
  }
  float gold = wave_sum64(g);

  // ---- coefficient pairs: fwd = column j of exp(T), bwd = row j ----
  v2f cf2[KSTATES / 2], cb2[KSTATES / 2];
#pragma unroll
  for (int k = 0; k < KSTATES / 2; ++k) {
    v2f f = {__expf(transitions[(2 * k + 0) * KSTATES + j]),
             __expf(transitions[(2 * k + 1) * KSTATES + j])};
    cf2[k] = f;
    v2f bb = {__expf(transitions[j * KSTATES + 2 * k + 0]),
              __expf(transitions[j * KSTATES + 2 * k + 1])};
    cb2[k] = bb;
  }

  const int m = sl >> 1;
  const int Nf = m;           // fwd steps consume t = 1..m
  const int Nb = sl - 1 - m;  // bwd steps consume t = sl-1..m+1 (Nb <= Nf)

  // ---- init (exp-space, normalized; per-chain log offsets C, renorm r) ----
  float a0v = start_trans[j] + emj[0];
  float m0 = wave_max64(a0v);
  float aF = __expf(a0v - m0);
  float CF = m0, rF = 1.0f;

  float b0v = end_trans[j];
  float mb = wave_max64(b0v);
  float aB = __expf(b0v - mb);
  float CB = mb, rB = 1.0f;

  // ---- emission rings, batch-prefetched one chunk ahead (per chain) ----
  float ringF[8], ringB[8];
#pragma unroll
  for (int q = 0; q < 8; ++q) {
    ringF[q] = emj[(size_t)min(1 + q, tmax) * KSTATES];
    ringB[q] = emj[(size_t)max(sl - 1 - q, 0) * KSTATES];
  }

  for (int n = 0; n < Nf; n += 8) {
    float nF[8], nB[8];
#pragma unroll
    for (int q = 0; q < 8; ++q) {
      nF[q] = emj[(size_t)min(1 + n + 8 + q, tmax) * KSTATES];
      nB[q] = emj[(size_t)max(sl - 1 - (n + 8 + q), 0) * KSTATES];
    }

#pragma unroll
    for (int q = 0; q < 8; ++q) {
      const bool doF = (n + q < Nf);  // wave-uniform scalar branches
      const bool doB = (n + q < Nb);
      if (doF || doB) {
        const int p = (n + q) & 1;
        float EF = 1.0f, EB = 1.0f;
        // publish both chains, one scheduling barrier, then both matvecs
        // (compiler interleaves the two independent read+fma streams).
        if (doF) {
          EF = __expf(ringF[q]);
          if (q == 0 || q == 4) {  // apply pending renorm exactly once
            EF *= rF;
            rF = 1.0f;
          }
          bufF[p][j] = aF;
        }
        if (doB) {
          EB = __expf(ringB[q]);
          if (q == 0 || q == 4) {
            EB *= rB;
            rB = 1.0f;
          }
          bufB[p][j] = aB * EB;  // bwd premultiplies emission before matvec
        }
        __builtin_amdgcn_wave_barrier();
        if (doF) {
          float s = matvec64(bufF[p], cf2);
          aF = s * EF;
          if (q == 3 || q == 7) {  // renorm every 4 steps, off critical path
            float ar = bcast0(aF);
            CF += __logf(ar);
            rF = __builtin_amdgcn_rcpf(ar);
          }
        }
        if (doB) {
          float s = matvec64(bufB[p], cb2);
          aB = s;
          if (q == 3 || q == 7) {
            float ar = bcast0(aB);
            CB += __logf(ar);
            rB = __builtin_amdgcn_rcpf(ar);
          }
        }
      }
    }

#pragma unroll
    for (int q = 0; q < 8; ++q) {
      ringF[q] = nF[q];
      ringB[q] = nB[q];
    }
  }

  aF *= rF;  // fold any pending renorms
  aB *= rB;

  // Z = sum_j alpha_m[j] * beta_m[j] — both states live in this wave.
  float v = aF * aB;
  float sum = wave_sum64(v);
  float fwd = CF + CB + __logf(sum);
  if (j == 0) atomicAdd(out, (fwd - gold) * inv_B);
}

extern "C" void kernel_launch(void* const* d_in, const int* in_sizes, int n_in,
                              void* d_out, int out_size, void* d_ws,
                              size_t ws_size, hipStream_t stream) {
  const float* emissions = (const float*)d_in[0];
  const float* transitions = (const float*)d_in[1];
  const float* start_trans = (const float*)d_in[2];
  const float* end_trans = (const float*)d_in[3];
  const int* labels = (const int*)d_in[4];
  const int* sent_len = (const int*)d_in[5];
  float* out = (float*)d_out;

  const int B = in_sizes[5];
  const int T = in_sizes[4] / B;

  hipMemsetAsync(out, 0, sizeof(float), stream);
  crf_kernel<<<B, KSTATES, 0, stream>>>(
      emissions, transitions, start_trans, end_trans, labels, sent_len, out, T,
      1.0f / (float)B);
}

// Round 9
// 354.687 us; speedup vs baseline: 1.3207x; 1.3207x over previous
//
#include <hip/hip_runtime.h>
#include <utility>

#define KSTATES 64

__device__ __forceinline__ float wave_max64(float v) {
#pragma unroll
  for (int off = 32; off; off >>= 1) v = fmaxf(v, __shfl_xor(v, off, 64));
  return v;
}

__device__ __forceinline__ float wave_sum64(float v) {
#pragma unroll
  for (int off = 32; off; off >>= 1) v += __shfl_xor(v, off, 64);
  return v;
}

__device__ __forceinline__ float bcast0(float v) {
  return __int_as_float(__builtin_amdgcn_readfirstlane(__float_as_int(v)));
}

// ds_swizzle BitMode or-broadcast: imm = (K<<5) | and_mask=0 -> every lane in
// a 32-lane half reads lane K of that half. The builtin demands an integral
// constant expression, so the 32-step loop is expanded via an integer pack
// (pack elements are ICEs; R7's #pragma-unroll variable was not).
template <int... Ks>
__device__ __forceinline__ void swz_fma32(int src, const float (&ch)[32],
                                          float& a0, float& a1, float& a2,
                                          float& a3,
                                          std::integer_sequence<int, Ks...>) {
  // 4 rotating accumulator chains, same association as R2: chain (K&3),
  // increasing K.
  ((
      [&](float& acc, float bc, float cc) { acc = fmaf(bc, cc, acc); }(
          (Ks & 3) == 0 ? a0 : (Ks & 3) == 1 ? a1 : (Ks & 3) == 2 ? a2 : a3,
          __int_as_float(__builtin_amdgcn_ds_swizzle(src, (Ks << 5))),
          ch[Ks])),
   ...);
}

// Broadcast matvec via ds_swizzle: LDS-pipe op with an IMMEDIATE pattern —
// no LDS write/turnaround (R0/R6 wall) and no readlane wait-state rate limit
// (R2/R5 wall). Returns pipeline in-order; compiler emits progressive
// lgkmcnt. Swizzle only permutes within 32-lane halves, so the other half's
// values come from one shfl_xor(av,32) (issued first; its latency hides
// under the first 32-swizzle half). Per-half coefficient tables ch1/ch2 keep
// every product term exactly paired; only the half-wave summation order
// differs from R2 (fp32 noise).
__device__ __forceinline__ float matvec_sw(float av, const float (&ch1)[32],
                                           const float (&ch2)[32]) {
  const int ai = __float_as_int(av);
  const int wi = __float_as_int(__shfl_xor(av, 32, 64));
  float a0 = 0.f, a1 = 0.f, a2 = 0.f, a3 = 0.f;
  swz_fma32(ai, ch1, a0, a1, a2, a3, std::make_integer_sequence<int, 32>{});
  swz_fma32(wi, ch2, a0, a1, a2, a3, std::make_integer_sequence<int, 32>{});
  return (a0 + a1) + (a2 + a3);
}

// One half-scan of the exp-space linear recurrence (structure identical to
// the verified R2 kernel; only the broadcast mechanism changed).
//   PREMUL=false (forward):  av = a;     matvec; a = s*E
//   PREMUL=true  (backward): av = b*E;   matvec; b = s
template <int DIR, bool PREMUL>
__device__ __forceinline__ float scan_half(const float* __restrict__ emj,
                                           int t0, int N, int tmax,
                                           const float (&ch1)[32],
                                           const float (&ch2)[32],
                                           float& state) {
  float C = 0.f, r = 1.0f;

  float ring[8];
#pragma unroll
  for (int q = 0; q < 8; ++q) {
    int tq = t0 + DIR * q;
    tq = min(max(tq, 0), tmax);
    ring[q] = emj[(size_t)tq * KSTATES];
  }

  for (int n = 0; n < N; n += 8) {
    float nring[8];
#pragma unroll
    for (int q = 0; q < 8; ++q) {
      int tq = t0 + DIR * (n + 8 + q);
      tq = min(max(tq, 0), tmax);
      nring[q] = emj[(size_t)tq * KSTATES];
    }

#pragma unroll
    for (int q = 0; q < 8; ++q) {
      if (n + q < N) {  // N is wave-uniform -> scalar branch, no divergence
        float E = __expf(ring[q]);
        if (q == 0 || q == 4) {  // apply pending renorm exactly once
          E *= r;
          r = 1.0f;
        }

        float av = PREMUL ? state * E : state;
        float s = matvec_sw(av, ch1, ch2);
        state = PREMUL ? s : s * E;

        if (q == 3 || q == 7) {  // renorm every 4 steps (off critical path)
          float ar = bcast0(state);
          C += __logf(ar);
          r = __builtin_amdgcn_rcpf(ar);
        }
      }
    }

#pragma unroll
    for (int q = 0; q < 8; ++q) ring[q] = nring[q];
  }

  state *= r;  // fold any pending renorm
  return C;
}

// 2 waves/block: wave 0 forward to meeting point m, wave 1 backward to m.
// Z = sum_j alpha_m[j]*beta_m[j]. 512 blocks x 2 waves = 1 wave/SIMD.
__global__ __launch_bounds__(128)
__attribute__((amdgpu_waves_per_eu(1, 1))) void crf_kernel(
    const float* __restrict__ emissions,   // [B, T, K]
    const float* __restrict__ transitions, // [K, K]
    const float* __restrict__ start_trans, // [K]
    const float* __restrict__ end_trans,   // [K]
    const int* __restrict__ labels,        // [B, T]
    const int* __restrict__ sent_len,      // [B]
    float* __restrict__ out,               // scalar
    int T, float inv_B) {
  const int b = blockIdx.x;
  const int tid = threadIdx.x;
  const int wid = tid >> 6;  // 0 = forward wave, 1 = backward wave
  const int j = tid & 63;    // state index == lane
  const int sl = sent_len[b];
  const int tmax = T - 1;

  __shared__ float Afin[KSTATES];  // alpha_m handoff
  __shared__ float Gpart[2];
  __shared__ float Cpart;

  const float* em = emissions + (size_t)b * T * KSTATES;
  const int* lbl = labels + (size_t)b * T;
  const float* emj = em + j;

  // ---- gold score: lane-parallel over time, split across both waves ----
  float g = 0.f;
#pragma unroll 4
  for (int t0 = tid; t0 < T; t0 += 128) {
    if (t0 < sl) {
      int lab = lbl[t0];
      float v = em[(size_t)t0 * KSTATES + lab];
      if (t0 == 0)
        v += start_trans[lab];
      else
        v += transitions[lbl[t0 - 1] * KSTATES + lab];
      if (t0 == sl - 1) v += end_trans[lab];
      g += v;
    }
  }
  float gw = wave_sum64(g);
  if (j == 0) Gpart[wid] = gw;

  const int m = sl >> 1;  // meeting point: fwd ends holding alpha_m
  const int h32 = j & 32; // this lane's half base (0 or 32)

  float state, Coff;
  float ch1[32], ch2[32];
  if (wid == 0) {
    // forward coeffs: c[i] = exp(T[i][j]) (column j).
    // ch1[k] = c[h32+k] (own half), ch2[k] = c[(h32^32)+k] (other half).
#pragma unroll
    for (int k = 0; k < 32; ++k) {
      ch1[k] = __expf(transitions[(h32 + k) * KSTATES + j]);
      ch2[k] = __expf(transitions[((h32 ^ 32) + k) * KSTATES + j]);
    }
    float a0 = start_trans[j] + emj[0];
    float m0 = wave_max64(a0);
    state = __expf(a0 - m0);
    Coff = m0 + scan_half<1, false>(emj, 1, m, tmax, ch1, ch2, state);
  } else {
    // backward coeffs: c[i] = exp(T[j][i]) (row j; 16KB matrix, L2-resident).
#pragma unroll
    for (int k = 0; k < 32; ++k) {
      ch1[k] = __expf(transitions[j * KSTATES + h32 + k]);
      ch2[k] = __expf(transitions[j * KSTATES + (h32 ^ 32) + k]);
    }
    float b0 = end_trans[j];
    float mb = wave_max64(b0);
    state = __expf(b0 - mb);
    Coff = mb + scan_half<-1, true>(emj, sl - 1, sl - 1 - m, tmax, ch1, ch2,
                                    state);
  }

  if (wid == 0) {
    Afin[j] = state;
    if (j == 0) Cpart = Coff;
  }
  __syncthreads();

  if (wid == 1) {
    // Z = sum_j alpha_m[j] * beta_m[j]
    float v = Afin[j] * state;
    float sum = wave_sum64(v);
    float fwd = Cpart + Coff + __logf(sum);
    if (j == 0) atomicAdd(out, (fwd - Gpart[0] - Gpart[1]) * inv_B);
  }
}

extern "C" void kernel_launch(void* const* d_in, const int* in_sizes, int n_in,
                              void* d_out, int out_size, void* d_ws,
                              size_t ws_size, hipStream_t stream) {
  const float* emissions = (const float*)d_in[0];
  const float* transitions = (const float*)d_in[1];
  const float* start_trans = (const float*)d_in[2];
  const float* end_trans = (const float*)d_in[3];
  const int* labels = (const int*)d_in[4];
  const int* sent_len = (const int*)d_in[5];
  float* out = (float*)d_out;

  const int B = in_sizes[5];
  const int T = in_sizes[4] / B;

  hipMemsetAsync(out, 0, sizeof(float), stream);
  crf_kernel<<<B, 128, 0, stream>>>(emissions, transitions, start_trans,
                                    end_trans, labels, sent_len, out, T,
                                    1.0f / (float)B);
}